// Round 15
// baseline (1140.093 us; speedup 1.0000x reference)
//
#include <hip/hip_runtime.h>
#include <hip/hip_bf16.h>
#include <stdint.h>
#include <stddef.h>

#define B 4096
#define S 13
#define NG 1024     // 4*HE == 4*HD
#define MEL 20000   // 80*250
#define MELP 20480  // padded to 80 col-tiles of 256 (grid 1280 = 8 XCD x 160)

typedef __attribute__((ext_vector_type(8))) short bf16x8;
typedef __attribute__((ext_vector_type(4))) float f32x4;

__device__ __forceinline__ void g2l16(void* lds, const void* g) {
    __builtin_amdgcn_global_load_lds(
        (const __attribute__((address_space(1))) void*)g,
        (__attribute__((address_space(3))) void*)lds, 16, 0, 0);
}

__device__ __forceinline__ float sigm(float x) { return 1.0f / (1.0f + expf(-x)); }
__device__ __forceinline__ float b2f(unsigned short u) {
    union { float f; unsigned int i; } x; x.i = ((unsigned)u) << 16; return x.f;
}
__device__ __forceinline__ unsigned short f2bu(float f) {
    __hip_bfloat16 h = __float2bfloat16(f);
    return *reinterpret_cast<unsigned short*>(&h);
}
__device__ __forceinline__ bf16x8 cvt8(f32x4 a, f32x4 b) {
    union { bf16x8 v; __hip_bfloat16 e[8]; } u;
    #pragma unroll
    for (int j = 0; j < 4; ++j) { u.e[j] = __float2bfloat16(a[j]); u.e[4 + j] = __float2bfloat16(b[j]); }
    return u.v;
}

// Block swizzle: XCD-bijective (nwg%8==0) + grouped rows (G=4).
__device__ __forceinline__ void swz_decode(int wg, int nwg, int nx, int& bx, int& by) {
    const int cpx = nwg >> 3;
    wg = (wg & 7) * cpx + (wg >> 3);
    const int gsz = nx * 4;
    const int grp = wg / gsz, rem = wg % gsz;
    by = grp * 4 + (rem & 3);
    bx = rem >> 2;
}

#define BAR() do { asm volatile("" ::: "memory"); \
    __builtin_amdgcn_s_barrier(); \
    __builtin_amdgcn_sched_barrier(0); } while (0)

// ---------------------------------------------------------------------------
// Shared 128x64 counted-vmcnt pipeline (4-buffer rotation, depth-3, BK=32).
// ---------------------------------------------------------------------------
#define P_DECL() \
    __shared__ __hip_bfloat16 As3[4][128 * 32]; \
    __shared__ __hip_bfloat16 Bs3[4][64 * 32]; \
    const int tid  = threadIdx.x; \
    const int lane = tid & 63; \
    const int wv   = tid >> 6; \
    const int l16  = lane & 15; \
    const int sr   = tid >> 2; \
    const int sc   = (((tid & 3) ^ ((tid >> 3) & 3)) << 3); \
    const int sl   = (((lane >> 4) ^ ((l16 >> 1) & 3)) << 3)

#define STG3(buf, k0) do { \
    g2l16(&As3[buf][sr * 32 + (tid & 3) * 8],         Ag + (size_t)sr * K + (k0) + sc); \
    g2l16(&As3[buf][(sr + 64) * 32 + (tid & 3) * 8],  Ag + (size_t)(sr + 64) * K + (k0) + sc); \
    g2l16(&Bs3[buf][sr * 32 + (tid & 3) * 8],         Wg + (size_t)sr * K + (k0) + sc); } while (0)

#define TILE3(cur, stg, k2, DO_STG) do { \
    const __hip_bfloat16* Ab = As3[cur]; \
    const __hip_bfloat16* Bb = Bs3[cur]; \
    bf16x8 af[2], bfr[4]; \
    _Pragma("unroll") for (int m = 0; m < 2; ++m) \
        af[m] = *(const bf16x8*)(Ab + (wv * 32 + m * 16 + l16) * 32 + sl); \
    _Pragma("unroll") for (int n = 0; n < 4; ++n) \
        bfr[n] = *(const bf16x8*)(Bb + (n * 16 + l16) * 32 + sl); \
    if (DO_STG) STG3(stg, k2); \
    __builtin_amdgcn_s_setprio(1); \
    _Pragma("unroll") for (int m = 0; m < 2; ++m) \
        _Pragma("unroll") for (int n = 0; n < 4; ++n) \
            acc[m][n] = __builtin_amdgcn_mfma_f32_16x16x32_bf16(af[m], bfr[n], acc[m][n], 0, 0, 0); \
    __builtin_amdgcn_s_setprio(0); \
} while (0)

#define PIPELINE(K) do { \
    const int nk = (K) >> 5; \
    STG3(0, 0); \
    STG3(1, 32); \
    STG3(2, 64); \
    asm volatile("s_waitcnt vmcnt(6)" ::: "memory"); \
    BAR(); \
    int cur = 0; \
    for (int t = 0; t < nk - 3; ++t) { \
        const int stg = (cur + 3) & 3; \
        TILE3(cur, stg, (t + 3) << 5, true); \
        asm volatile("s_waitcnt vmcnt(6)" ::: "memory"); \
        BAR(); \
        cur = (cur + 1) & 3; \
    } \
    TILE3(cur, 0, 0, false); \
    asm volatile("s_waitcnt vmcnt(3)" ::: "memory"); \
    BAR(); \
    cur = (cur + 1) & 3; \
    TILE3(cur, 0, 0, false); \
    asm volatile("s_waitcnt vmcnt(0)" ::: "memory"); \
    BAR(); \
    cur = (cur + 1) & 3; \
    TILE3(cur, 0, 0, false); \
} while (0)

// ---------------------------------------------------------------------------
// Generic 128x64 counted-vmcnt GEMM: C = A @ W^T + bias, relu, bf16/f32 out.
// remap4: permuted gate col np -> unit(np)*4 + gate(np) (for dec_persist).
// ---------------------------------------------------------------------------
__global__ __launch_bounds__(256, 2) void gemm3(
    const __hip_bfloat16* __restrict__ A,
    const __hip_bfloat16* __restrict__ W,
    const float* __restrict__ bias,
    float* __restrict__ Cf,
    __hip_bfloat16* __restrict__ Cbf,
    int N, int K, int ldc, int relu, int nx, int remap4)
{
    P_DECL();
    int bx, by;
    swz_decode(blockIdx.x, gridDim.x, nx, bx, by);
    const int brow = by * 128, bcol = bx * 64;
    const __hip_bfloat16* Ag = A + (size_t)brow * K;
    const __hip_bfloat16* Wg = W + (size_t)bcol * K;
    f32x4 acc[2][4] = {};

    PIPELINE(K);

    const int r4 = (lane >> 4) * 4;
    #pragma unroll
    for (int m = 0; m < 2; ++m) {
        #pragma unroll
        for (int n = 0; n < 4; ++n) {
            const int col = bcol + n * 16 + l16;
            if (col >= N) continue;
            const float bv = bias ? bias[col] : 0.0f;
            int colw = col;
            if (remap4) {
                const int u = ((col >> 6) << 4) + (col & 15);
                const int g = (col >> 4) & 3;
                colw = u * 4 + g;
            }
            #pragma unroll
            for (int r = 0; r < 4; ++r) {
                const int row = brow + wv * 32 + m * 16 + r4 + r;
                float v = acc[m][n][r] + bv;
                if (relu) v = v > 0.0f ? v : 0.0f;
                if (Cf)  Cf[(size_t)row * ldc + colw] = v;
                if (Cbf) Cbf[(size_t)row * ldc + colw] = __float2bfloat16(v);
            }
        }
    }
}

// ---------------------------------------------------------------------------
// Encoder fused GEMM + LSTM cell (per-col bias) + enc_score atomic fusion.
// ---------------------------------------------------------------------------
__global__ __launch_bounds__(256, 2) void gemm_lstm3(
    const __hip_bfloat16* __restrict__ A,
    const __hip_bfloat16* __restrict__ W,
    const float* __restrict__ bias,
    float* __restrict__ c,
    __hip_bfloat16* __restrict__ hb1, int s1,
    __hip_bfloat16* __restrict__ hb2, int s2,
    int K,
    const float* __restrict__ aw,
    float* __restrict__ score)
{
    P_DECL();
    int bx, by;
    swz_decode(blockIdx.x, gridDim.x, 16, bx, by);
    const int brow = by * 128, bcol = bx * 64;
    const __hip_bfloat16* Ag = A + (size_t)brow * K;
    const __hip_bfloat16* Wg = W + (size_t)bcol * K;
    f32x4 acc[2][4] = {};

    PIPELINE(K);

    const int r4 = (lane >> 4) * 4;
    const int unit = bx * 16 + l16;
    const float b0 = bias[bcol + l16];
    const float b1 = bias[bcol + 16 + l16];
    const float b2 = bias[bcol + 32 + l16];
    const float b3 = bias[bcol + 48 + l16];
    const float awe = score ? aw[256 + unit] : 0.0f;
    float ps[2][4];
    #pragma unroll
    for (int m = 0; m < 2; ++m) {
        #pragma unroll
        for (int r = 0; r < 4; ++r) {
            const int row = brow + wv * 32 + m * 16 + r4 + r;
            const float gi = acc[m][0][r] + b0;
            const float gf = acc[m][1][r] + b1;
            const float gg = acc[m][2][r] + b2;
            const float go = acc[m][3][r] + b3;
            const size_t ci = (size_t)row * 256 + unit;
            const float c2 = sigm(gf) * c[ci] + sigm(gi) * tanhf(gg);
            const float h2 = sigm(go) * tanhf(c2);
            c[ci] = c2;
            ps[m][r] = h2 * awe;
            const __hip_bfloat16 hb = __float2bfloat16(h2);
            hb1[(size_t)row * s1 + unit] = hb;
            hb2[(size_t)row * s2 + unit] = hb;
        }
    }
    if (score) {
        #pragma unroll
        for (int m = 0; m < 2; ++m) {
            #pragma unroll
            for (int r = 0; r < 4; ++r) {
                float v = ps[m][r];
                v += __shfl_xor(v, 1);
                v += __shfl_xor(v, 2);
                v += __shfl_xor(v, 4);
                v += __shfl_xor(v, 8);
                if (l16 == 0) {
                    const int row = brow + wv * 32 + m * 16 + r4 + r;
                    atomicAdd(&score[(size_t)row * S], v);
                }
            }
        }
    }
}

// ---------------------------------------------------------------------------
// Persistent decoder: 64 blocks x 512 threads; each block owns 64 rows and
// runs all 13 steps with NO inter-block sync (recurrence is row-local).
// h in swizzled LDS (32 KB), c in VGPRs, Wdh streamed L2->VGPR (no staging),
// gctx4 = per-row gate bias in [row][unit*4+gate] layout.
// Wave w owns permuted-cols [w*128, w*128+128) = units 32w..32w+31, 4 gates.
// ---------------------------------------------------------------------------
__global__ __launch_bounds__(512, 2) void dec_persist(
    const __hip_bfloat16* __restrict__ h0,     // B x 256 (h_n from encoder)
    const __hip_bfloat16* __restrict__ Wdh,    // 1024 x 256 gate-permuted
    const float* __restrict__ gctx4,           // B x 1024, [row][unit*4+gate]
    const float* __restrict__ cin,             // B x 256 f32 (c_n from encoder)
    __hip_bfloat16* __restrict__ dec_out)      // B x 3328
{
    __shared__ char Hs[8 * 64 * 64];           // [kt][row][64B], slot-XOR swizzled
    const int tid  = threadIdx.x;
    const int lane = tid & 63;
    const int w    = tid >> 6;                 // wave 0..7
    const int l16  = lane & 15;
    const int lk   = lane >> 4;                // 0..3
    const int brow = blockIdx.x * 64;

    // initial h -> swizzled LDS
    #pragma unroll
    for (int i = 0; i < 4; ++i) {
        const int linear = tid + i * 512;      // 16B-chunk id, 0..2047
        const int row  = (linear >> 2) & 63;
        const int kt   = linear >> 8;
        const int slot = linear & 3;
        const bf16x8 v = *(const bf16x8*)(h0 + (size_t)(brow + row) * 256 + kt * 32 + slot * 8);
        *(bf16x8*)(Hs + kt * 4096 + row * 64 + ((slot ^ ((row >> 1) & 3)) << 4)) = v;
    }

    // c -> registers: cells (m, h2, r): row = m*16 + lk*4 + r, unit = 32w + h2*16 + l16
    float creg[4][2][4];
    #pragma unroll
    for (int m = 0; m < 4; ++m)
        #pragma unroll
        for (int h2 = 0; h2 < 2; ++h2)
            #pragma unroll
            for (int r = 0; r < 4; ++r)
                creg[m][h2][r] = cin[(size_t)(brow + m * 16 + lk * 4 + r) * 256 + 32 * w + h2 * 16 + l16];

    const __hip_bfloat16* Wb = Wdh + (size_t)(w * 128) * 256;
    __syncthreads();

    for (int t = 0; t < S; ++t) {
        f32x4 acc[4][8] = {};
        #pragma unroll
        for (int kt = 0; kt < 8; ++kt) {
            bf16x8 af[4], bfr[8];
            #pragma unroll
            for (int m = 0; m < 4; ++m) {
                const int row = m * 16 + l16;
                af[m] = *(const bf16x8*)(Hs + kt * 4096 + row * 64 + ((lk ^ ((row >> 1) & 3)) << 4));
            }
            #pragma unroll
            for (int n = 0; n < 8; ++n)
                bfr[n] = *(const bf16x8*)(Wb + (size_t)(n * 16 + l16) * 256 + kt * 32 + lk * 8);
            #pragma unroll
            for (int m = 0; m < 4; ++m)
                #pragma unroll
                for (int n = 0; n < 8; ++n)
                    acc[m][n] = __builtin_amdgcn_mfma_f32_16x16x32_bf16(af[m], bfr[n], acc[m][n], 0, 0, 0);
        }
        __syncthreads();   // all waves done reading old h
        #pragma unroll
        for (int m = 0; m < 4; ++m) {
            #pragma unroll
            for (int r = 0; r < 4; ++r) {
                const int row = m * 16 + lk * 4 + r;
                #pragma unroll
                for (int h2 = 0; h2 < 2; ++h2) {
                    const int unit = 32 * w + h2 * 16 + l16;
                    const f32x4 g4 = *(const f32x4*)(gctx4 + (size_t)(brow + row) * 1024 + unit * 4);
                    const float gi = acc[m][h2 * 4 + 0][r] + g4[0];
                    const float gf = acc[m][h2 * 4 + 1][r] + g4[1];
                    const float gg = acc[m][h2 * 4 + 2][r] + g4[2];
                    const float go = acc[m][h2 * 4 + 3][r] + g4[3];
                    float& cc = creg[m][h2][r];
                    const float c2 = sigm(gf) * cc + sigm(gi) * tanhf(gg);
                    const float hh = sigm(go) * tanhf(c2);
                    cc = c2;
                    const unsigned short hb = f2bu(hh);
                    const int kk = h2 * 16 + l16;         // k' within wave's kt=w tile
                    const int slot = kk >> 3;
                    *(unsigned short*)(Hs + w * 4096 + row * 64 +
                        ((slot ^ ((row >> 1) & 3)) << 4) + (kk & 7) * 2) = hb;
                    dec_out[(size_t)(brow + row) * 3328 + t * 256 + unit] =
                        *reinterpret_cast<const __hip_bfloat16*>(&hb);
                }
            }
        }
        __syncthreads();   // new h visible to all waves
    }
}

// ---------------------------------------------------------------------------
// 256x256 multi-phase counted-vmcnt GEMM (FC2): BK=32, 8 waves (2Mx4N),
// 4-buffer LDS rotation (128 KB), depth-3 prefetch, slot-XOR swizzle, setprio.
// Super-tiled XCD grid map (R12: best measured, 219 us, FETCH 123 MB).
// ---------------------------------------------------------------------------
__global__ __launch_bounds__(512, 2) void gemm256(
    const __hip_bfloat16* __restrict__ A,
    const __hip_bfloat16* __restrict__ W,
    const float* __restrict__ bias,
    float* __restrict__ Cf,
    int N, int K, int ldc, int nx)
{
    __shared__ __hip_bfloat16 As[4][256 * 32];
    __shared__ __hip_bfloat16 Bs[4][256 * 32];
    const int tid  = threadIdx.x;
    const int lane = tid & 63;
    const int wv = tid >> 6, wr = wv >> 2, wc = wv & 3;
    const int l16 = lane & 15;
    int bx, by;
    {   // super-tiled XCD map: xcd -> 10 sequential 4x4 super-tiles
        const int xcd = blockIdx.x & 7;
        const int lid = blockIdx.x >> 3;
        const int st  = lid >> 4;
        const int w   = lid & 15;
        const int gst = xcd * 10 + st;
        const int sbx = gst >> 2;
        const int sby = gst & 3;
        bx = sbx * 4 + (w & 3);
        by = sby * 4 + (w >> 2);
    }
    const int brow = by * 256, bcol = bx * 256;
    const __hip_bfloat16* Ag = A + (size_t)brow * K;
    const __hip_bfloat16* Wg = W + (size_t)bcol * K;
    const int sr = tid >> 2;
    const int sc = (((tid & 3) ^ ((tid >> 3) & 3)) << 3);
    const int sd = tid * 8;
    const int sl = (((lane >> 4) ^ ((l16 >> 1) & 3)) << 3);
    f32x4 acc[8][4] = {};
    const int nk = K >> 5;

    #define STG_A(buf, k0) do { \
        g2l16(&As[buf][sd],        Ag + (size_t)sr * K + (k0) + sc);         \
        g2l16(&As[buf][4096 + sd], Ag + (size_t)(sr + 128) * K + (k0) + sc); } while (0)
    #define STG_B(buf, k0) do { \
        g2l16(&Bs[buf][sd],        Wg + (size_t)sr * K + (k0) + sc);         \
        g2l16(&Bs[buf][4096 + sd], Wg + (size_t)(sr + 128) * K + (k0) + sc); } while (0)

    #define TILE(cur, stg, k2, DO_STG) do {                                    \
        const __hip_bfloat16* Ab = As[cur];                                    \
        const __hip_bfloat16* Bb = Bs[cur];                                    \
        bf16x8 bfr[4], af[4];                                                  \
        _Pragma("unroll") for (int n = 0; n < 4; ++n)                          \
            bfr[n] = *(const bf16x8*)(Bb + (wc * 64 + n * 16 + l16) * 32 + sl);\
        _Pragma("unroll") for (int m = 0; m < 4; ++m)                          \
            af[m] = *(const bf16x8*)(Ab + (wr * 128 + m * 16 + l16) * 32 + sl);\
        if (DO_STG) STG_A(stg, k2);                                            \
        BAR();                                                                 \
        __builtin_amdgcn_s_setprio(1);                                         \
        _Pragma("unroll") for (int m = 0; m < 4; ++m)                          \
            _Pragma("unroll") for (int n = 0; n < 4; ++n)                      \
                acc[m][n] = __builtin_amdgcn_mfma_f32_16x16x32_bf16(           \
                    af[m], bfr[n], acc[m][n], 0, 0, 0);                        \
        __builtin_amdgcn_s_setprio(0);                                         \
        BAR();                                                                 \
        _Pragma("unroll") for (int m = 0; m < 4; ++m)                          \
            af[m] = *(const bf16x8*)(Ab + (wr * 128 + (m + 4) * 16 + l16) * 32 + sl); \
        if (DO_STG) STG_B(stg, k2);                                            \
        BAR();                                                                 \
        __builtin_amdgcn_s_setprio(1);                                         \
        _Pragma("unroll") for (int m = 0; m < 4; ++m)                          \
            _Pragma("unroll") for (int n = 0; n < 4; ++n)                      \
                acc[m + 4][n] = __builtin_amdgcn_mfma_f32_16x16x32_bf16(       \
                    af[m], bfr[n], acc[m + 4][n], 0, 0, 0);                    \
        __builtin_amdgcn_s_setprio(0);                                         \
    } while (0)

    STG_A(0, 0);  STG_B(0, 0);
    STG_A(1, 32); STG_B(1, 32);
    STG_A(2, 64); STG_B(2, 64);
    asm volatile("s_waitcnt vmcnt(8)" ::: "memory");
    BAR();
    int cur = 0;
    for (int t = 0; t < nk - 3; ++t) {
        const int stg = (cur + 3) & 3;
        TILE(cur, stg, (t + 3) << 5, true);
        asm volatile("s_waitcnt vmcnt(8)" ::: "memory");
        BAR();
        cur = (cur + 1) & 3;
    }
    TILE(cur, 0, 0, false);
    asm volatile("s_waitcnt vmcnt(4)" ::: "memory");
    BAR();
    cur = (cur + 1) & 3;
    TILE(cur, 0, 0, false);
    asm volatile("s_waitcnt vmcnt(0)" ::: "memory");
    BAR();
    cur = (cur + 1) & 3;
    TILE(cur, 0, 0, false);

    const int r4 = (lane >> 4) * 4;
    #pragma unroll
    for (int m = 0; m < 8; ++m) {
        #pragma unroll
        for (int n = 0; n < 4; ++n) {
            const int col = bcol + wc * 64 + n * 16 + l16;
            if (col >= N) continue;
            const float bv = bias[col];
            #pragma unroll
            for (int r = 0; r < 4; ++r) {
                const int row = brow + wr * 128 + m * 16 + r4 + r;
                Cf[(size_t)row * ldc + col] = acc[m][n][r] + bv;
            }
        }
    }
}

// ---------------------------------------------------------------------------
// Merged prep kernel (region-partitioned).
// ---------------------------------------------------------------------------
__device__ __forceinline__ int unperm(int np) {
    const int u = ((np >> 6) << 4) + (np & 15);
    const int g = (np >> 4) & 3;
    return g * 256 + u;
}

#define N_W2   ((long long)MELP * 1024 / 8)
#define N_W1   ((long long)NG * 3328 / 8)
#define N_WE   ((long long)NG * 384 / 8)
#define N_WD   ((long long)NG * 512 / 8)
#define N_EMB  ((long long)B * S * 32)
#define N_INIT ((long long)B * 256)
#define N_F2B  ((long long)MELP)
#define N_BP   ((long long)NG)
#define N_ES   ((long long)B * S)
#define N_PREP (N_W2 + N_W1 + N_WE + N_WD + N_EMB + N_INIT + N_F2B + N_BP + N_ES)

__global__ void prep_all(
    const int* __restrict__ text, const float* __restrict__ surp,
    const float* __restrict__ emb, const float* __restrict__ sw,
    const float* __restrict__ sb,
    const float* __restrict__ ew_ih, const float* __restrict__ ew_hh,
    const float* __restrict__ eb_ih, const float* __restrict__ eb_hh,
    const float* __restrict__ dw_ih, const float* __restrict__ dw_hh,
    const float* __restrict__ db_ih, const float* __restrict__ db_hh,
    const float* __restrict__ f1w, const float* __restrict__ f2w,
    const float* __restrict__ f2b, const float* __restrict__ init_in,
    const float* __restrict__ ab,
    __hip_bfloat16* __restrict__ Wenc,
    __hip_bfloat16* __restrict__ Wdc, __hip_bfloat16* __restrict__ Wdh,
    __hip_bfloat16* __restrict__ W1, __hip_bfloat16* __restrict__ W2,
    float* __restrict__ f2bp, float* __restrict__ be, float* __restrict__ bd,
    __hip_bfloat16* __restrict__ xall, float* __restrict__ c_buf,
    float* __restrict__ enc_score)
{
    long long id = (long long)blockIdx.x * 256 + threadIdx.x;
    if (id < N_W2) {
        const long long i8 = id * 8;
        bf16x8 v;
        if (i8 < (long long)MEL * 1024) {
            v = cvt8(*(const f32x4*)(f2w + i8), *(const f32x4*)(f2w + i8 + 4));
        } else {
            union { bf16x8 w; __hip_bfloat16 e[8]; } u;
            #pragma unroll
            for (int j = 0; j < 8; ++j) u.e[j] = __float2bfloat16(0.0f);
            v = u.w;
        }
        *(bf16x8*)(W2 + i8) = v;
        return;
    }
    id -= N_W2;
    if (id < N_W1) {
        const long long i8 = id * 8;
        *(bf16x8*)(W1 + i8) = cvt8(*(const f32x4*)(f1w + i8), *(const f32x4*)(f1w + i8 + 4));
        return;
    }
    id -= N_W1;
    if (id < N_WE) {
        const int idx = (int)(id * 8);
        const int np = idx / 384, k = idx % 384;
        const int n = unperm(np);
        const float* src = (k < 128) ? (ew_ih + n * 128 + k) : (ew_hh + n * 256 + (k - 128));
        *(bf16x8*)(Wenc + idx) = cvt8(*(const f32x4*)src, *(const f32x4*)(src + 4));
        return;
    }
    id -= N_WE;
    if (id < N_WD) {    // split pack: Wdc (ctx part) | Wdh (hh part)
        const int idx = (int)(id * 8);
        const int np = idx / 512, k = idx % 512;
        const int n = unperm(np);
        if (k < 256) {
            const float* src = dw_ih + n * 384 + 128 + k;
            *(bf16x8*)(Wdc + np * 256 + k) = cvt8(*(const f32x4*)src, *(const f32x4*)(src + 4));
        } else {
            const float* src = dw_hh + n * 256 + (k - 256);
            *(bf16x8*)(Wdh + np * 256 + (k - 256)) = cvt8(*(const f32x4*)src, *(const f32x4*)(src + 4));
        }
        return;
    }
    id -= N_WD;
    if (id < N_EMB) {
        const int idx = (int)id;
        const int jj = (idx & 31) * 4;
        const int rest = idx >> 5;
        const int b = rest % B;
        const int s = rest / B;
        const float sp = surp[b * S + s];
        const f32x4 e4 = *(const f32x4*)(emb + (size_t)text[b * S + s] * 128 + jj);
        const f32x4 w4 = *(const f32x4*)(sw + jj);
        const f32x4 b4 = *(const f32x4*)(sb + jj);
        __hip_bfloat16* dst = xall + ((size_t)s * B + b) * 384 + jj;
        #pragma unroll
        for (int i = 0; i < 4; ++i) dst[i] = __float2bfloat16(e4[i] + sp * w4[i] + b4[i]);
        return;
    }
    id -= N_EMB;
    if (id < N_INIT) {
        const int idx = (int)id;
        c_buf[idx] = 0.0f;
        const int b = idx >> 8, jj = idx & 255;
        xall[(size_t)b * 384 + 128 + jj] = __float2bfloat16(0.0f);
        return;
    }
    id -= N_INIT;
    if (id < N_F2B) {
        const int idx = (int)id;
        f2bp[idx] = (idx < MEL) ? f2b[idx] : 0.0f;
        return;
    }
    id -= N_F2B;
    if (id < N_BP) {
        const int np = (int)id;
        const int n = unperm(np);
        be[np] = eb_ih[n] + eb_hh[n];
        float s = db_ih[n] + db_hh[n];
        for (int k = 0; k < 128; ++k) s += dw_ih[n * 384 + k] * init_in[k];
        bd[np] = s;
        return;
    }
    id -= N_BP;
    if (id < N_ES) {
        enc_score[id] = ab[0];
        return;
    }
}

// ---------------------------------------------------------------------------
// One-shot attention: w = softmax(enc_score[b,:]) (h-independent — softmax is
// shift-invariant per row); context[b,:] = sum_s w[s] * enc_out[b,s,:].
// ---------------------------------------------------------------------------
__global__ void attn_once(const __hip_bfloat16* __restrict__ enc_out,
                          const float* __restrict__ enc_score,
                          __hip_bfloat16* __restrict__ ctx) {
    int b = (blockIdx.x * 256 + threadIdx.x) >> 6;
    int lane = threadIdx.x & 63;
    if (b >= B) return;
    float sc[S], mx = -1e30f;
    #pragma unroll
    for (int t = 0; t < S; ++t) { sc[t] = enc_score[b * S + t]; mx = fmaxf(mx, sc[t]); }
    float sum = 0.0f;
    #pragma unroll
    for (int t = 0; t < S; ++t) { sc[t] = expf(sc[t] - mx); sum += sc[t]; }
    const float inv = 1.0f / sum;
    float c0 = 0.f, c1 = 0.f, c2 = 0.f, c3 = 0.f;
    #pragma unroll
    for (int t = 0; t < S; ++t) {
        const ushort4 e4 = *(const ushort4*)(enc_out + ((size_t)b * S + t) * 256 + lane * 4);
        const float w = sc[t] * inv;
        c0 += w * b2f(e4.x); c1 += w * b2f(e4.y);
        c2 += w * b2f(e4.z); c3 += w * b2f(e4.w);
    }
    ushort4 o4 = { f2bu(c0), f2bu(c1), f2bu(c2), f2bu(c3) };
    *(ushort4*)(ctx + (size_t)b * 256 + lane * 4) = o4;
}

// ---------------------------------------------------------------------------
#define CDIV(a, b) (((a) + (b) - 1) / (b))

extern "C" void kernel_launch(void* const* d_in, const int* in_sizes, int n_in,
                              void* d_out, int out_size, void* d_ws, size_t ws_size,
                              hipStream_t stream) {
    const int*   text    = (const int*)  d_in[0];
    const float* surp    = (const float*)d_in[1];
    const float* emb     = (const float*)d_in[2];
    const float* sw      = (const float*)d_in[3];
    const float* sb      = (const float*)d_in[4];
    const float* ew_ih   = (const float*)d_in[5];
    const float* ew_hh   = (const float*)d_in[6];
    const float* eb_ih   = (const float*)d_in[7];
    const float* eb_hh   = (const float*)d_in[8];
    const float* aw      = (const float*)d_in[9];
    const float* ab      = (const float*)d_in[10];
    const float* dw_ih   = (const float*)d_in[11];
    const float* dw_hh   = (const float*)d_in[12];
    const float* db_ih   = (const float*)d_in[13];
    const float* db_hh   = (const float*)d_in[14];
    const float* f1w     = (const float*)d_in[15];
    const float* f1b     = (const float*)d_in[16];
    const float* f2w     = (const float*)d_in[17];
    const float* f2b     = (const float*)d_in[18];
    const float* init_in = (const float*)d_in[19];
    float* out = (float*)d_out;

    char* p = (char*)d_ws;
    auto alloc = [&](size_t bytes) {
        void* r = (void*)p;
        p += (bytes + 255) & ~(size_t)255;
        return r;
    };
    __hip_bfloat16* Wenc      = (__hip_bfloat16*)alloc((size_t)NG * 384 * 2);
    __hip_bfloat16* Wdc       = (__hip_bfloat16*)alloc((size_t)NG * 256 * 2);
    __hip_bfloat16* Wdh       = (__hip_bfloat16*)alloc((size_t)NG * 256 * 2);
    __hip_bfloat16* W1        = (__hip_bfloat16*)alloc((size_t)NG * 3328 * 2);
    __hip_bfloat16* W2        = (__hip_bfloat16*)alloc((size_t)MELP * 1024 * 2);
    float*          f2bp      = (float*)alloc((size_t)MELP * 4);
    float*          be        = (float*)alloc((size_t)NG * 4);
    float*          bd        = (float*)alloc((size_t)NG * 4);
    __hip_bfloat16* xall      = (__hip_bfloat16*)alloc((size_t)S * B * 384 * 2);
    __hip_bfloat16* enc_out   = (__hip_bfloat16*)alloc((size_t)B * S * 256 * 2);
    float*          enc_score = (float*)alloc((size_t)B * S * 4);
    float*          c_buf     = (float*)alloc((size_t)B * 256 * 4);
    __hip_bfloat16* ctx       = (__hip_bfloat16*)alloc((size_t)B * 256 * 2);
    float*          gctx      = (float*)alloc((size_t)B * NG * 4);
    __hip_bfloat16* hdec      = (__hip_bfloat16*)alloc((size_t)B * 256 * 2);
    __hip_bfloat16* dec_out   = (__hip_bfloat16*)alloc((size_t)B * 3328 * 2);
    __hip_bfloat16* hfc       = (__hip_bfloat16*)alloc((size_t)B * 1024 * 2);
    (void)ws_size; (void)in_sizes; (void)n_in; (void)out_size;

    // --- merged prep ---
    prep_all<<<(int)CDIV(N_PREP, 256), 256, 0, stream>>>(
        text, surp, emb, sw, sb, ew_ih, ew_hh, eb_ih, eb_hh,
        dw_ih, dw_hh, db_ih, db_hh, f1w, f2w, f2b, init_in, ab,
        Wenc, Wdc, Wdh, W1, W2, f2bp, be, bd, xall, c_buf, enc_score);

    // --- encoder: 13 fused GEMM+cell steps (enc_score fused via atomics) ---
    for (int t = 0; t < S; ++t) {
        __hip_bfloat16* hb1; int s1;
        if (t < S - 1) { hb1 = xall + ((size_t)(t + 1) * B * 384) + 128; s1 = 384; }
        else           { hb1 = hdec; s1 = 256; }
        gemm_lstm3<<<512, 256, 0, stream>>>(
            xall + (size_t)t * B * 384, Wenc, be, c_buf,
            hb1, s1, enc_out + (size_t)t * 256, S * 256, 384,
            aw, enc_score + t);
    }

    // --- attention (once): context + its gate projection (remapped layout) ---
    attn_once<<<CDIV(B * 64, 256), 256, 0, stream>>>(enc_out, enc_score, ctx);
    gemm3<<<(NG / 64) * (B / 128), 256, 0, stream>>>(
        ctx, Wdc, bd, gctx, (__hip_bfloat16*)nullptr, NG, 256, NG, 0, NG / 64, 1);

    // --- decoder: ONE persistent kernel, 13 steps, row-local recurrence ---
    dec_persist<<<64, 512, 0, stream>>>(hdec, Wdh, gctx, c_buf, dec_out);

    // --- FC1: relu(dec_out @ f1w.T + f1b) -> bf16 hfc ---
    gemm3<<<(NG / 64) * (B / 128), 256, 0, stream>>>(
        dec_out, W1, f1b, (float*)nullptr, hfc, NG, 3328, NG, 1, NG / 64, 0);

    // --- FC2: 256x256 counted-vmcnt kernel (super-tiled XCD map) -> out ---
    gemm256<<<(MELP / 256) * (B / 256), 512, 0, stream>>>(
        hfc, W2, f2bp, out, MEL, 1024, MEL, MELP / 256);
}

// Round 16
// 608.898 us; speedup vs baseline: 1.8724x; 1.8724x over previous
//
#include <hip/hip_runtime.h>
#include <hip/hip_bf16.h>
#include <stdint.h>
#include <stddef.h>

#define B 4096
#define S 13
#define NG 1024     // 4*HE == 4*HD
#define MEL 20000   // 80*250
#define MELP 20480  // padded to 80 col-tiles of 256 (grid 1280 = 8 XCD x 160)

typedef __attribute__((ext_vector_type(8))) short bf16x8;
typedef __attribute__((ext_vector_type(4))) float f32x4;

__device__ __forceinline__ void g2l16(void* lds, const void* g) {
    __builtin_amdgcn_global_load_lds(
        (const __attribute__((address_space(1))) void*)g,
        (__attribute__((address_space(3))) void*)lds, 16, 0, 0);
}

__device__ __forceinline__ float sigm(float x) { return 1.0f / (1.0f + expf(-x)); }
__device__ __forceinline__ float b2f(unsigned short u) {
    union { float f; unsigned int i; } x; x.i = ((unsigned)u) << 16; return x.f;
}
__device__ __forceinline__ unsigned short f2bu(float f) {
    __hip_bfloat16 h = __float2bfloat16(f);
    return *reinterpret_cast<unsigned short*>(&h);
}
__device__ __forceinline__ bf16x8 cvt8(f32x4 a, f32x4 b) {
    union { bf16x8 v; __hip_bfloat16 e[8]; } u;
    #pragma unroll
    for (int j = 0; j < 4; ++j) { u.e[j] = __float2bfloat16(a[j]); u.e[4 + j] = __float2bfloat16(b[j]); }
    return u.v;
}

// Block swizzle: XCD-bijective (nwg%8==0) + grouped rows (G=4).
__device__ __forceinline__ void swz_decode(int wg, int nwg, int nx, int& bx, int& by) {
    const int cpx = nwg >> 3;
    wg = (wg & 7) * cpx + (wg >> 3);
    const int gsz = nx * 4;
    const int grp = wg / gsz, rem = wg % gsz;
    by = grp * 4 + (rem & 3);
    bx = rem >> 2;
}

#define BAR() do { asm volatile("" ::: "memory"); \
    __builtin_amdgcn_s_barrier(); \
    __builtin_amdgcn_sched_barrier(0); } while (0)

// ---------------------------------------------------------------------------
// Shared 128x64 counted-vmcnt pipeline (4-buffer rotation, depth-3, BK=32).
// ---------------------------------------------------------------------------
#define P_DECL() \
    __shared__ __hip_bfloat16 As3[4][128 * 32]; \
    __shared__ __hip_bfloat16 Bs3[4][64 * 32]; \
    const int tid  = threadIdx.x; \
    const int lane = tid & 63; \
    const int wv   = tid >> 6; \
    const int l16  = lane & 15; \
    const int sr   = tid >> 2; \
    const int sc   = (((tid & 3) ^ ((tid >> 3) & 3)) << 3); \
    const int sl   = (((lane >> 4) ^ ((l16 >> 1) & 3)) << 3)

#define STG3(buf, k0) do { \
    g2l16(&As3[buf][sr * 32 + (tid & 3) * 8],         Ag + (size_t)sr * K + (k0) + sc); \
    g2l16(&As3[buf][(sr + 64) * 32 + (tid & 3) * 8],  Ag + (size_t)(sr + 64) * K + (k0) + sc); \
    g2l16(&Bs3[buf][sr * 32 + (tid & 3) * 8],         Wg + (size_t)sr * K + (k0) + sc); } while (0)

#define TILE3(cur, stg, k2, DO_STG) do { \
    const __hip_bfloat16* Ab = As3[cur]; \
    const __hip_bfloat16* Bb = Bs3[cur]; \
    bf16x8 af[2], bfr[4]; \
    _Pragma("unroll") for (int m = 0; m < 2; ++m) \
        af[m] = *(const bf16x8*)(Ab + (wv * 32 + m * 16 + l16) * 32 + sl); \
    _Pragma("unroll") for (int n = 0; n < 4; ++n) \
        bfr[n] = *(const bf16x8*)(Bb + (n * 16 + l16) * 32 + sl); \
    if (DO_STG) STG3(stg, k2); \
    __builtin_amdgcn_s_setprio(1); \
    _Pragma("unroll") for (int m = 0; m < 2; ++m) \
        _Pragma("unroll") for (int n = 0; n < 4; ++n) \
            acc[m][n] = __builtin_amdgcn_mfma_f32_16x16x32_bf16(af[m], bfr[n], acc[m][n], 0, 0, 0); \
    __builtin_amdgcn_s_setprio(0); \
} while (0)

#define PIPELINE(K) do { \
    const int nk = (K) >> 5; \
    STG3(0, 0); \
    STG3(1, 32); \
    STG3(2, 64); \
    asm volatile("s_waitcnt vmcnt(6)" ::: "memory"); \
    BAR(); \
    int cur = 0; \
    for (int t = 0; t < nk - 3; ++t) { \
        const int stg = (cur + 3) & 3; \
        TILE3(cur, stg, (t + 3) << 5, true); \
        asm volatile("s_waitcnt vmcnt(6)" ::: "memory"); \
        BAR(); \
        cur = (cur + 1) & 3; \
    } \
    TILE3(cur, 0, 0, false); \
    asm volatile("s_waitcnt vmcnt(3)" ::: "memory"); \
    BAR(); \
    cur = (cur + 1) & 3; \
    TILE3(cur, 0, 0, false); \
    asm volatile("s_waitcnt vmcnt(0)" ::: "memory"); \
    BAR(); \
    cur = (cur + 1) & 3; \
    TILE3(cur, 0, 0, false); \
} while (0)

// ---------------------------------------------------------------------------
// Generic 128x64 counted-vmcnt GEMM: C = A @ W^T + bias, relu, bf16/f32 out.
// Used for FC1 and the once-per-launch gctx projection.
// ---------------------------------------------------------------------------
__global__ __launch_bounds__(256, 2) void gemm3(
    const __hip_bfloat16* __restrict__ A,
    const __hip_bfloat16* __restrict__ W,
    const float* __restrict__ bias,
    float* __restrict__ Cf,
    __hip_bfloat16* __restrict__ Cbf,
    int N, int K, int ldc, int relu, int nx)
{
    P_DECL();
    int bx, by;
    swz_decode(blockIdx.x, gridDim.x, nx, bx, by);
    const int brow = by * 128, bcol = bx * 64;
    const __hip_bfloat16* Ag = A + (size_t)brow * K;
    const __hip_bfloat16* Wg = W + (size_t)bcol * K;
    f32x4 acc[2][4] = {};

    PIPELINE(K);

    const int r4 = (lane >> 4) * 4;
    #pragma unroll
    for (int m = 0; m < 2; ++m) {
        #pragma unroll
        for (int n = 0; n < 4; ++n) {
            const int col = bcol + n * 16 + l16;
            if (col >= N) continue;
            const float bv = bias ? bias[col] : 0.0f;
            #pragma unroll
            for (int r = 0; r < 4; ++r) {
                const int row = brow + wv * 32 + m * 16 + r4 + r;
                float v = acc[m][n][r] + bv;
                if (relu) v = v > 0.0f ? v : 0.0f;
                if (Cf)  Cf[(size_t)row * ldc + col] = v;
                if (Cbf) Cbf[(size_t)row * ldc + col] = __float2bfloat16(v);
            }
        }
    }
}

// ---------------------------------------------------------------------------
// Encoder fused GEMM + LSTM cell (per-col bias) + enc_score atomic fusion.
// ---------------------------------------------------------------------------
__global__ __launch_bounds__(256, 2) void gemm_lstm3(
    const __hip_bfloat16* __restrict__ A,
    const __hip_bfloat16* __restrict__ W,
    const float* __restrict__ bias,
    float* __restrict__ c,
    __hip_bfloat16* __restrict__ hb1, int s1,
    __hip_bfloat16* __restrict__ hb2, int s2,
    int K,
    const float* __restrict__ aw,
    float* __restrict__ score)
{
    P_DECL();
    int bx, by;
    swz_decode(blockIdx.x, gridDim.x, 16, bx, by);
    const int brow = by * 128, bcol = bx * 64;
    const __hip_bfloat16* Ag = A + (size_t)brow * K;
    const __hip_bfloat16* Wg = W + (size_t)bcol * K;
    f32x4 acc[2][4] = {};

    PIPELINE(K);

    const int r4 = (lane >> 4) * 4;
    const int unit = bx * 16 + l16;
    const float b0 = bias[bcol + l16];
    const float b1 = bias[bcol + 16 + l16];
    const float b2 = bias[bcol + 32 + l16];
    const float b3 = bias[bcol + 48 + l16];
    const float awe = score ? aw[256 + unit] : 0.0f;
    float ps[2][4];
    #pragma unroll
    for (int m = 0; m < 2; ++m) {
        #pragma unroll
        for (int r = 0; r < 4; ++r) {
            const int row = brow + wv * 32 + m * 16 + r4 + r;
            const float gi = acc[m][0][r] + b0;
            const float gf = acc[m][1][r] + b1;
            const float gg = acc[m][2][r] + b2;
            const float go = acc[m][3][r] + b3;
            const size_t ci = (size_t)row * 256 + unit;
            const float c2 = sigm(gf) * c[ci] + sigm(gi) * tanhf(gg);
            const float h2 = sigm(go) * tanhf(c2);
            c[ci] = c2;
            ps[m][r] = h2 * awe;
            const __hip_bfloat16 hb = __float2bfloat16(h2);
            hb1[(size_t)row * s1 + unit] = hb;
            hb2[(size_t)row * s2 + unit] = hb;
        }
    }
    if (score) {
        #pragma unroll
        for (int m = 0; m < 2; ++m) {
            #pragma unroll
            for (int r = 0; r < 4; ++r) {
                float v = ps[m][r];
                v += __shfl_xor(v, 1);
                v += __shfl_xor(v, 2);
                v += __shfl_xor(v, 4);
                v += __shfl_xor(v, 8);
                if (l16 == 0) {
                    const int row = brow + wv * 32 + m * 16 + r4 + r;
                    atomicAdd(&score[(size_t)row * S], v);
                }
            }
        }
    }
}

// ---------------------------------------------------------------------------
// Decoder fused GEMM + LSTM cell: K=256 (h @ Whh^T), per-ROW gate bias gctx
// (context projection + all biases, precomputed once — attention weights are
// h-independent because softmax is shift-invariant per row).
// ---------------------------------------------------------------------------
__global__ __launch_bounds__(256, 2) void gemm_lstm_dec(
    const __hip_bfloat16* __restrict__ A,      // hdec[t&1], B x 256 bf16
    const __hip_bfloat16* __restrict__ W,      // Wdh, 1024 x 256 (permuted)
    const float* __restrict__ gctx,            // B x 1024 (permuted cols)
    float* __restrict__ c,
    __hip_bfloat16* __restrict__ hb1,          // hdec[(t+1)&1], stride 256
    __hip_bfloat16* __restrict__ hb2, int s2,  // dec_out + t*256, stride 3328
    int K)
{
    P_DECL();
    int bx, by;
    swz_decode(blockIdx.x, gridDim.x, 16, bx, by);
    const int brow = by * 128, bcol = bx * 64;
    const __hip_bfloat16* Ag = A + (size_t)brow * K;
    const __hip_bfloat16* Wg = W + (size_t)bcol * K;
    f32x4 acc[2][4] = {};

    PIPELINE(K);

    const int r4 = (lane >> 4) * 4;
    const int unit = bx * 16 + l16;
    #pragma unroll
    for (int m = 0; m < 2; ++m) {
        #pragma unroll
        for (int r = 0; r < 4; ++r) {
            const int row = brow + wv * 32 + m * 16 + r4 + r;
            const float* g = gctx + (size_t)row * NG + bcol;
            const float gi = acc[m][0][r] + g[l16];
            const float gf = acc[m][1][r] + g[16 + l16];
            const float gg = acc[m][2][r] + g[32 + l16];
            const float go = acc[m][3][r] + g[48 + l16];
            const size_t ci = (size_t)row * 256 + unit;
            const float c2 = sigm(gf) * c[ci] + sigm(gi) * tanhf(gg);
            const float h2 = sigm(go) * tanhf(c2);
            c[ci] = c2;
            const __hip_bfloat16 hb = __float2bfloat16(h2);
            hb1[(size_t)row * 256 + unit] = hb;
            hb2[(size_t)row * s2 + unit] = hb;
        }
    }
}

// ---------------------------------------------------------------------------
// 256x256 multi-phase counted-vmcnt GEMM (FC2): BK=32, 8 waves (2Mx4N),
// 4-buffer LDS rotation (128 KB), depth-3 prefetch, slot-XOR swizzle, setprio.
// Super-tiled XCD grid map (R12: best measured, 219 us, FETCH 123 MB).
// ---------------------------------------------------------------------------
__global__ __launch_bounds__(512, 2) void gemm256(
    const __hip_bfloat16* __restrict__ A,
    const __hip_bfloat16* __restrict__ W,
    const float* __restrict__ bias,
    float* __restrict__ Cf,
    int N, int K, int ldc, int nx)
{
    __shared__ __hip_bfloat16 As[4][256 * 32];
    __shared__ __hip_bfloat16 Bs[4][256 * 32];
    const int tid  = threadIdx.x;
    const int lane = tid & 63;
    const int wv = tid >> 6, wr = wv >> 2, wc = wv & 3;
    const int l16 = lane & 15;
    int bx, by;
    {   // super-tiled XCD map: xcd -> 10 sequential 4x4 super-tiles
        const int xcd = blockIdx.x & 7;
        const int lid = blockIdx.x >> 3;
        const int st  = lid >> 4;
        const int w   = lid & 15;
        const int gst = xcd * 10 + st;
        const int sbx = gst >> 2;
        const int sby = gst & 3;
        bx = sbx * 4 + (w & 3);
        by = sby * 4 + (w >> 2);
    }
    const int brow = by * 256, bcol = bx * 256;
    const __hip_bfloat16* Ag = A + (size_t)brow * K;
    const __hip_bfloat16* Wg = W + (size_t)bcol * K;
    const int sr = tid >> 2;
    const int sc = (((tid & 3) ^ ((tid >> 3) & 3)) << 3);
    const int sd = tid * 8;
    const int sl = (((lane >> 4) ^ ((l16 >> 1) & 3)) << 3);
    f32x4 acc[8][4] = {};
    const int nk = K >> 5;

    #define STG_A(buf, k0) do { \
        g2l16(&As[buf][sd],        Ag + (size_t)sr * K + (k0) + sc);         \
        g2l16(&As[buf][4096 + sd], Ag + (size_t)(sr + 128) * K + (k0) + sc); } while (0)
    #define STG_B(buf, k0) do { \
        g2l16(&Bs[buf][sd],        Wg + (size_t)sr * K + (k0) + sc);         \
        g2l16(&Bs[buf][4096 + sd], Wg + (size_t)(sr + 128) * K + (k0) + sc); } while (0)

    #define TILE(cur, stg, k2, DO_STG) do {                                    \
        const __hip_bfloat16* Ab = As[cur];                                    \
        const __hip_bfloat16* Bb = Bs[cur];                                    \
        bf16x8 bfr[4], af[4];                                                  \
        _Pragma("unroll") for (int n = 0; n < 4; ++n)                          \
            bfr[n] = *(const bf16x8*)(Bb + (wc * 64 + n * 16 + l16) * 32 + sl);\
        _Pragma("unroll") for (int m = 0; m < 4; ++m)                          \
            af[m] = *(const bf16x8*)(Ab + (wr * 128 + m * 16 + l16) * 32 + sl);\
        if (DO_STG) STG_A(stg, k2);                                            \
        BAR();                                                                 \
        __builtin_amdgcn_s_setprio(1);                                         \
        _Pragma("unroll") for (int m = 0; m < 4; ++m)                          \
            _Pragma("unroll") for (int n = 0; n < 4; ++n)                      \
                acc[m][n] = __builtin_amdgcn_mfma_f32_16x16x32_bf16(           \
                    af[m], bfr[n], acc[m][n], 0, 0, 0);                        \
        __builtin_amdgcn_s_setprio(0);                                         \
        BAR();                                                                 \
        _Pragma("unroll") for (int m = 0; m < 4; ++m)                          \
            af[m] = *(const bf16x8*)(Ab + (wr * 128 + (m + 4) * 16 + l16) * 32 + sl); \
        if (DO_STG) STG_B(stg, k2);                                            \
        BAR();                                                                 \
        __builtin_amdgcn_s_setprio(1);                                         \
        _Pragma("unroll") for (int m = 0; m < 4; ++m)                          \
            _Pragma("unroll") for (int n = 0; n < 4; ++n)                      \
                acc[m + 4][n] = __builtin_amdgcn_mfma_f32_16x16x32_bf16(       \
                    af[m], bfr[n], acc[m + 4][n], 0, 0, 0);                    \
        __builtin_amdgcn_s_setprio(0);                                         \
    } while (0)

    STG_A(0, 0);  STG_B(0, 0);
    STG_A(1, 32); STG_B(1, 32);
    STG_A(2, 64); STG_B(2, 64);
    asm volatile("s_waitcnt vmcnt(8)" ::: "memory");
    BAR();
    int cur = 0;
    for (int t = 0; t < nk - 3; ++t) {
        const int stg = (cur + 3) & 3;
        TILE(cur, stg, (t + 3) << 5, true);
        asm volatile("s_waitcnt vmcnt(8)" ::: "memory");
        BAR();
        cur = (cur + 1) & 3;
    }
    TILE(cur, 0, 0, false);
    asm volatile("s_waitcnt vmcnt(4)" ::: "memory");
    BAR();
    cur = (cur + 1) & 3;
    TILE(cur, 0, 0, false);
    asm volatile("s_waitcnt vmcnt(0)" ::: "memory");
    BAR();
    cur = (cur + 1) & 3;
    TILE(cur, 0, 0, false);

    const int r4 = (lane >> 4) * 4;
    #pragma unroll
    for (int m = 0; m < 8; ++m) {
        #pragma unroll
        for (int n = 0; n < 4; ++n) {
            const int col = bcol + wc * 64 + n * 16 + l16;
            if (col >= N) continue;
            const float bv = bias[col];
            #pragma unroll
            for (int r = 0; r < 4; ++r) {
                const int row = brow + wr * 128 + m * 16 + r4 + r;
                Cf[(size_t)row * ldc + col] = acc[m][n][r] + bv;
            }
        }
    }
}

// ---------------------------------------------------------------------------
// Merged prep kernel (region-partitioned).
// ---------------------------------------------------------------------------
__device__ __forceinline__ int unperm(int np) {
    const int u = ((np >> 6) << 4) + (np & 15);
    const int g = (np >> 4) & 3;
    return g * 256 + u;
}

#define N_W2   ((long long)MELP * 1024 / 8)
#define N_W1   ((long long)NG * 3328 / 8)
#define N_WE   ((long long)NG * 384 / 8)
#define N_WD   ((long long)NG * 512 / 8)
#define N_EMB  ((long long)B * S * 32)
#define N_INIT ((long long)B * 256)
#define N_F2B  ((long long)MELP)
#define N_BP   ((long long)NG)
#define N_ES   ((long long)B * S)
#define N_PREP (N_W2 + N_W1 + N_WE + N_WD + N_EMB + N_INIT + N_F2B + N_BP + N_ES)

__global__ void prep_all(
    const int* __restrict__ text, const float* __restrict__ surp,
    const float* __restrict__ emb, const float* __restrict__ sw,
    const float* __restrict__ sb,
    const float* __restrict__ ew_ih, const float* __restrict__ ew_hh,
    const float* __restrict__ eb_ih, const float* __restrict__ eb_hh,
    const float* __restrict__ dw_ih, const float* __restrict__ dw_hh,
    const float* __restrict__ db_ih, const float* __restrict__ db_hh,
    const float* __restrict__ f1w, const float* __restrict__ f2w,
    const float* __restrict__ f2b, const float* __restrict__ init_in,
    const float* __restrict__ ab,
    __hip_bfloat16* __restrict__ Wenc,
    __hip_bfloat16* __restrict__ Wdc, __hip_bfloat16* __restrict__ Wdh,
    __hip_bfloat16* __restrict__ W1, __hip_bfloat16* __restrict__ W2,
    float* __restrict__ f2bp, float* __restrict__ be, float* __restrict__ bd,
    __hip_bfloat16* __restrict__ xall, float* __restrict__ c_buf,
    float* __restrict__ enc_score)
{
    long long id = (long long)blockIdx.x * 256 + threadIdx.x;
    if (id < N_W2) {
        const long long i8 = id * 8;
        bf16x8 v;
        if (i8 < (long long)MEL * 1024) {
            v = cvt8(*(const f32x4*)(f2w + i8), *(const f32x4*)(f2w + i8 + 4));
        } else {
            union { bf16x8 w; __hip_bfloat16 e[8]; } u;
            #pragma unroll
            for (int j = 0; j < 8; ++j) u.e[j] = __float2bfloat16(0.0f);
            v = u.w;
        }
        *(bf16x8*)(W2 + i8) = v;
        return;
    }
    id -= N_W2;
    if (id < N_W1) {
        const long long i8 = id * 8;
        *(bf16x8*)(W1 + i8) = cvt8(*(const f32x4*)(f1w + i8), *(const f32x4*)(f1w + i8 + 4));
        return;
    }
    id -= N_W1;
    if (id < N_WE) {
        const int idx = (int)(id * 8);
        const int np = idx / 384, k = idx % 384;
        const int n = unperm(np);
        const float* src = (k < 128) ? (ew_ih + n * 128 + k) : (ew_hh + n * 256 + (k - 128));
        *(bf16x8*)(Wenc + idx) = cvt8(*(const f32x4*)src, *(const f32x4*)(src + 4));
        return;
    }
    id -= N_WE;
    if (id < N_WD) {    // split pack: Wdc (ctx part) | Wdh (hh part)
        const int idx = (int)(id * 8);
        const int np = idx / 512, k = idx % 512;
        const int n = unperm(np);
        if (k < 256) {
            const float* src = dw_ih + n * 384 + 128 + k;
            *(bf16x8*)(Wdc + np * 256 + k) = cvt8(*(const f32x4*)src, *(const f32x4*)(src + 4));
        } else {
            const float* src = dw_hh + n * 256 + (k - 256);
            *(bf16x8*)(Wdh + np * 256 + (k - 256)) = cvt8(*(const f32x4*)src, *(const f32x4*)(src + 4));
        }
        return;
    }
    id -= N_WD;
    if (id < N_EMB) {
        const int idx = (int)id;
        const int jj = (idx & 31) * 4;
        const int rest = idx >> 5;
        const int b = rest % B;
        const int s = rest / B;
        const float sp = surp[b * S + s];
        const f32x4 e4 = *(const f32x4*)(emb + (size_t)text[b * S + s] * 128 + jj);
        const f32x4 w4 = *(const f32x4*)(sw + jj);
        const f32x4 b4 = *(const f32x4*)(sb + jj);
        __hip_bfloat16* dst = xall + ((size_t)s * B + b) * 384 + jj;
        #pragma unroll
        for (int i = 0; i < 4; ++i) dst[i] = __float2bfloat16(e4[i] + sp * w4[i] + b4[i]);
        return;
    }
    id -= N_EMB;
    if (id < N_INIT) {
        const int idx = (int)id;
        c_buf[idx] = 0.0f;
        const int b = idx >> 8, jj = idx & 255;
        xall[(size_t)b * 384 + 128 + jj] = __float2bfloat16(0.0f);
        return;
    }
    id -= N_INIT;
    if (id < N_F2B) {
        const int idx = (int)id;
        f2bp[idx] = (idx < MEL) ? f2b[idx] : 0.0f;
        return;
    }
    id -= N_F2B;
    if (id < N_BP) {
        const int np = (int)id;
        const int n = unperm(np);
        be[np] = eb_ih[n] + eb_hh[n];
        float s = db_ih[n] + db_hh[n];
        for (int k = 0; k < 128; ++k) s += dw_ih[n * 384 + k] * init_in[k];
        bd[np] = s;
        return;
    }
    id -= N_BP;
    if (id < N_ES) {
        enc_score[id] = ab[0];
        return;
    }
}

// ---------------------------------------------------------------------------
// One-shot attention: w = softmax(enc_score[b,:]) (h-independent — softmax is
// shift-invariant per row); context[b,:] = sum_s w[s] * enc_out[b,s,:].
// ---------------------------------------------------------------------------
__global__ void attn_once(const __hip_bfloat16* __restrict__ enc_out,
                          const float* __restrict__ enc_score,
                          __hip_bfloat16* __restrict__ ctx) {
    int b = (blockIdx.x * 256 + threadIdx.x) >> 6;
    int lane = threadIdx.x & 63;
    if (b >= B) return;
    float sc[S], mx = -1e30f;
    #pragma unroll
    for (int t = 0; t < S; ++t) { sc[t] = enc_score[b * S + t]; mx = fmaxf(mx, sc[t]); }
    float sum = 0.0f;
    #pragma unroll
    for (int t = 0; t < S; ++t) { sc[t] = expf(sc[t] - mx); sum += sc[t]; }
    const float inv = 1.0f / sum;
    float c0 = 0.f, c1 = 0.f, c2 = 0.f, c3 = 0.f;
    #pragma unroll
    for (int t = 0; t < S; ++t) {
        const ushort4 e4 = *(const ushort4*)(enc_out + ((size_t)b * S + t) * 256 + lane * 4);
        const float w = sc[t] * inv;
        c0 += w * b2f(e4.x); c1 += w * b2f(e4.y);
        c2 += w * b2f(e4.z); c3 += w * b2f(e4.w);
    }
    ushort4 o4 = { f2bu(c0), f2bu(c1), f2bu(c2), f2bu(c3) };
    *(ushort4*)(ctx + (size_t)b * 256 + lane * 4) = o4;
}

// ---------------------------------------------------------------------------
#define CDIV(a, b) (((a) + (b) - 1) / (b))

extern "C" void kernel_launch(void* const* d_in, const int* in_sizes, int n_in,
                              void* d_out, int out_size, void* d_ws, size_t ws_size,
                              hipStream_t stream) {
    const int*   text    = (const int*)  d_in[0];
    const float* surp    = (const float*)d_in[1];
    const float* emb     = (const float*)d_in[2];
    const float* sw      = (const float*)d_in[3];
    const float* sb      = (const float*)d_in[4];
    const float* ew_ih   = (const float*)d_in[5];
    const float* ew_hh   = (const float*)d_in[6];
    const float* eb_ih   = (const float*)d_in[7];
    const float* eb_hh   = (const float*)d_in[8];
    const float* aw      = (const float*)d_in[9];
    const float* ab      = (const float*)d_in[10];
    const float* dw_ih   = (const float*)d_in[11];
    const float* dw_hh   = (const float*)d_in[12];
    const float* db_ih   = (const float*)d_in[13];
    const float* db_hh   = (const float*)d_in[14];
    const float* f1w     = (const float*)d_in[15];
    const float* f1b     = (const float*)d_in[16];
    const float* f2w     = (const float*)d_in[17];
    const float* f2b     = (const float*)d_in[18];
    const float* init_in = (const float*)d_in[19];
    float* out = (float*)d_out;

    char* p = (char*)d_ws;
    auto alloc = [&](size_t bytes) {
        void* r = (void*)p;
        p += (bytes + 255) & ~(size_t)255;
        return r;
    };
    __hip_bfloat16* Wenc      = (__hip_bfloat16*)alloc((size_t)NG * 384 * 2);
    __hip_bfloat16* Wdc       = (__hip_bfloat16*)alloc((size_t)NG * 256 * 2);
    __hip_bfloat16* Wdh       = (__hip_bfloat16*)alloc((size_t)NG * 256 * 2);
    __hip_bfloat16* W1        = (__hip_bfloat16*)alloc((size_t)NG * 3328 * 2);
    __hip_bfloat16* W2        = (__hip_bfloat16*)alloc((size_t)MELP * 1024 * 2);
    float*          f2bp      = (float*)alloc((size_t)MELP * 4);
    float*          be        = (float*)alloc((size_t)NG * 4);
    float*          bd        = (float*)alloc((size_t)NG * 4);
    __hip_bfloat16* xall      = (__hip_bfloat16*)alloc((size_t)S * B * 384 * 2);
    __hip_bfloat16* enc_out   = (__hip_bfloat16*)alloc((size_t)B * S * 256 * 2);
    float*          enc_score = (float*)alloc((size_t)B * S * 4);
    float*          c_buf     = (float*)alloc((size_t)B * 256 * 4);
    __hip_bfloat16* ctx       = (__hip_bfloat16*)alloc((size_t)B * 256 * 2);
    float*          gctx      = (float*)alloc((size_t)B * NG * 4);
    __hip_bfloat16* hdec      = (__hip_bfloat16*)alloc((size_t)2 * B * 256 * 2);
    __hip_bfloat16* dec_out   = (__hip_bfloat16*)alloc((size_t)B * 3328 * 2);
    __hip_bfloat16* hfc       = (__hip_bfloat16*)alloc((size_t)B * 1024 * 2);
    (void)ws_size; (void)in_sizes; (void)n_in; (void)out_size;

    // --- merged prep ---
    prep_all<<<(int)CDIV(N_PREP, 256), 256, 0, stream>>>(
        text, surp, emb, sw, sb, ew_ih, ew_hh, eb_ih, eb_hh,
        dw_ih, dw_hh, db_ih, db_hh, f1w, f2w, f2b, init_in, ab,
        Wenc, Wdc, Wdh, W1, W2, f2bp, be, bd, xall, c_buf, enc_score);

    // --- encoder: 13 fused GEMM+cell steps (enc_score fused via atomics) ---
    for (int t = 0; t < S; ++t) {
        __hip_bfloat16* hb1; int s1;
        if (t < S - 1) { hb1 = xall + ((size_t)(t + 1) * B * 384) + 128; s1 = 384; }
        else           { hb1 = hdec; s1 = 256; }
        gemm_lstm3<<<512, 256, 0, stream>>>(
            xall + (size_t)t * B * 384, Wenc, be, c_buf,
            hb1, s1, enc_out + (size_t)t * 256, S * 256, 384,
            aw, enc_score + t);
    }

    // --- attention (once): context + its gate projection ---
    attn_once<<<CDIV(B * 64, 256), 256, 0, stream>>>(enc_out, enc_score, ctx);
    gemm3<<<(NG / 64) * (B / 128), 256, 0, stream>>>(
        ctx, Wdc, bd, gctx, (__hip_bfloat16*)nullptr, NG, 256, NG, 0, NG / 64);

    // --- decoder: 13 fused GEMM+cell steps, K=256, per-row bias gctx ---
    for (int t = 0; t < S; ++t) {
        gemm_lstm_dec<<<512, 256, 0, stream>>>(
            hdec + (size_t)(t & 1) * B * 256, Wdh, gctx, c_buf,
            hdec + (size_t)((t + 1) & 1) * B * 256,
            dec_out + (size_t)t * 256, 3328, 256);
    }

    // --- FC1: relu(dec_out @ f1w.T + f1b) -> bf16 hfc ---
    gemm3<<<(NG / 64) * (B / 128), 256, 0, stream>>>(
        dec_out, W1, f1b, (float*)nullptr, hfc, NG, 3328, NG, 1, NG / 64);

    // --- FC2: 256x256 counted-vmcnt kernel (super-tiled XCD map) -> out ---
    gemm256<<<(MELP / 256) * (B / 256), 512, 0, stream>>>(
        hfc, W2, f2bp, out, MEL, 1024, MEL, MELP / 256);
}

// Round 17
// 596.648 us; speedup vs baseline: 1.9108x; 1.0205x over previous
//
#include <hip/hip_runtime.h>
#include <hip/hip_bf16.h>
#include <stdint.h>
#include <stddef.h>

#define B 4096
#define S 13
#define NG 1024     // 4*HE == 4*HD
#define MEL 20000   // 80*250
#define MELP 20480  // padded to 80 col-tiles of 256 (grid 1280 = 8 XCD x 160)

typedef __attribute__((ext_vector_type(8))) short bf16x8;
typedef __attribute__((ext_vector_type(4))) float f32x4;

__device__ __forceinline__ void g2l16(void* lds, const void* g) {
    __builtin_amdgcn_global_load_lds(
        (const __attribute__((address_space(1))) void*)g,
        (__attribute__((address_space(3))) void*)lds, 16, 0, 0);
}

__device__ __forceinline__ float sigm(float x) { return 1.0f / (1.0f + expf(-x)); }
__device__ __forceinline__ float b2f(unsigned short u) {
    union { float f; unsigned int i; } x; x.i = ((unsigned)u) << 16; return x.f;
}
__device__ __forceinline__ unsigned short f2bu(float f) {
    __hip_bfloat16 h = __float2bfloat16(f);
    return *reinterpret_cast<unsigned short*>(&h);
}
__device__ __forceinline__ bf16x8 cvt8(f32x4 a, f32x4 b) {
    union { bf16x8 v; __hip_bfloat16 e[8]; } u;
    #pragma unroll
    for (int j = 0; j < 4; ++j) { u.e[j] = __float2bfloat16(a[j]); u.e[4 + j] = __float2bfloat16(b[j]); }
    return u.v;
}

// Block swizzle: XCD-bijective (nwg%8==0) + grouped rows (G=4).
__device__ __forceinline__ void swz_decode(int wg, int nwg, int nx, int& bx, int& by) {
    const int cpx = nwg >> 3;
    wg = (wg & 7) * cpx + (wg >> 3);
    const int gsz = nx * 4;
    const int grp = wg / gsz, rem = wg % gsz;
    by = grp * 4 + (rem & 3);
    bx = rem >> 2;
}

#define BAR() do { asm volatile("" ::: "memory"); \
    __builtin_amdgcn_s_barrier(); \
    __builtin_amdgcn_sched_barrier(0); } while (0)

// ---------------------------------------------------------------------------
// Shared 128x64 counted-vmcnt pipeline (4-buffer rotation, depth-3, BK=32).
// ---------------------------------------------------------------------------
#define P_DECL() \
    __shared__ __hip_bfloat16 As3[4][128 * 32]; \
    __shared__ __hip_bfloat16 Bs3[4][64 * 32]; \
    const int tid  = threadIdx.x; \
    const int lane = tid & 63; \
    const int wv   = tid >> 6; \
    const int l16  = lane & 15; \
    const int sr   = tid >> 2; \
    const int sc   = (((tid & 3) ^ ((tid >> 3) & 3)) << 3); \
    const int sl   = (((lane >> 4) ^ ((l16 >> 1) & 3)) << 3)

#define STG3(buf, k0) do { \
    g2l16(&As3[buf][sr * 32 + (tid & 3) * 8],         Ag + (size_t)sr * K + (k0) + sc); \
    g2l16(&As3[buf][(sr + 64) * 32 + (tid & 3) * 8],  Ag + (size_t)(sr + 64) * K + (k0) + sc); \
    g2l16(&Bs3[buf][sr * 32 + (tid & 3) * 8],         Wg + (size_t)sr * K + (k0) + sc); } while (0)

#define TILE3(cur, stg, k2, DO_STG) do { \
    const __hip_bfloat16* Ab = As3[cur]; \
    const __hip_bfloat16* Bb = Bs3[cur]; \
    bf16x8 af[2], bfr[4]; \
    _Pragma("unroll") for (int m = 0; m < 2; ++m) \
        af[m] = *(const bf16x8*)(Ab + (wv * 32 + m * 16 + l16) * 32 + sl); \
    _Pragma("unroll") for (int n = 0; n < 4; ++n) \
        bfr[n] = *(const bf16x8*)(Bb + (n * 16 + l16) * 32 + sl); \
    if (DO_STG) STG3(stg, k2); \
    __builtin_amdgcn_s_setprio(1); \
    _Pragma("unroll") for (int m = 0; m < 2; ++m) \
        _Pragma("unroll") for (int n = 0; n < 4; ++n) \
            acc[m][n] = __builtin_amdgcn_mfma_f32_16x16x32_bf16(af[m], bfr[n], acc[m][n], 0, 0, 0); \
    __builtin_amdgcn_s_setprio(0); \
} while (0)

#define PIPELINE(K) do { \
    const int nk = (K) >> 5; \
    STG3(0, 0); \
    STG3(1, 32); \
    STG3(2, 64); \
    asm volatile("s_waitcnt vmcnt(6)" ::: "memory"); \
    BAR(); \
    int cur = 0; \
    for (int t = 0; t < nk - 3; ++t) { \
        const int stg = (cur + 3) & 3; \
        TILE3(cur, stg, (t + 3) << 5, true); \
        asm volatile("s_waitcnt vmcnt(6)" ::: "memory"); \
        BAR(); \
        cur = (cur + 1) & 3; \
    } \
    TILE3(cur, 0, 0, false); \
    asm volatile("s_waitcnt vmcnt(3)" ::: "memory"); \
    BAR(); \
    cur = (cur + 1) & 3; \
    TILE3(cur, 0, 0, false); \
    asm volatile("s_waitcnt vmcnt(0)" ::: "memory"); \
    BAR(); \
    cur = (cur + 1) & 3; \
    TILE3(cur, 0, 0, false); \
} while (0)

// ---------------------------------------------------------------------------
// Generic 128x64 counted-vmcnt GEMM: C = A @ W^T + bias, relu, bf16/f32 out.
// ---------------------------------------------------------------------------
__global__ __launch_bounds__(256, 2) void gemm3(
    const __hip_bfloat16* __restrict__ A,
    const __hip_bfloat16* __restrict__ W,
    const float* __restrict__ bias,
    float* __restrict__ Cf,
    __hip_bfloat16* __restrict__ Cbf,
    int N, int K, int ldc, int relu, int nx)
{
    P_DECL();
    int bx, by;
    swz_decode(blockIdx.x, gridDim.x, nx, bx, by);
    const int brow = by * 128, bcol = bx * 64;
    const __hip_bfloat16* Ag = A + (size_t)brow * K;
    const __hip_bfloat16* Wg = W + (size_t)bcol * K;
    f32x4 acc[2][4] = {};

    PIPELINE(K);

    const int r4 = (lane >> 4) * 4;
    #pragma unroll
    for (int m = 0; m < 2; ++m) {
        #pragma unroll
        for (int n = 0; n < 4; ++n) {
            const int col = bcol + n * 16 + l16;
            if (col >= N) continue;
            const float bv = bias ? bias[col] : 0.0f;
            #pragma unroll
            for (int r = 0; r < 4; ++r) {
                const int row = brow + wv * 32 + m * 16 + r4 + r;
                float v = acc[m][n][r] + bv;
                if (relu) v = v > 0.0f ? v : 0.0f;
                if (Cf)  Cf[(size_t)row * ldc + col] = v;
                if (Cbf) Cbf[(size_t)row * ldc + col] = __float2bfloat16(v);
            }
        }
    }
}

// ---------------------------------------------------------------------------
// Encoder fused GEMM + LSTM cell (per-col bias) + enc_score atomic fusion.
// ---------------------------------------------------------------------------
__global__ __launch_bounds__(256, 2) void gemm_lstm3(
    const __hip_bfloat16* __restrict__ A,
    const __hip_bfloat16* __restrict__ W,
    const float* __restrict__ bias,
    float* __restrict__ c,
    __hip_bfloat16* __restrict__ hb1, int s1,
    __hip_bfloat16* __restrict__ hb2, int s2,
    int K,
    const float* __restrict__ aw,
    float* __restrict__ score)
{
    P_DECL();
    int bx, by;
    swz_decode(blockIdx.x, gridDim.x, 16, bx, by);
    const int brow = by * 128, bcol = bx * 64;
    const __hip_bfloat16* Ag = A + (size_t)brow * K;
    const __hip_bfloat16* Wg = W + (size_t)bcol * K;
    f32x4 acc[2][4] = {};

    PIPELINE(K);

    const int r4 = (lane >> 4) * 4;
    const int unit = bx * 16 + l16;
    const float b0 = bias[bcol + l16];
    const float b1 = bias[bcol + 16 + l16];
    const float b2 = bias[bcol + 32 + l16];
    const float b3 = bias[bcol + 48 + l16];
    const float awe = score ? aw[256 + unit] : 0.0f;
    float ps[2][4];
    #pragma unroll
    for (int m = 0; m < 2; ++m) {
        #pragma unroll
        for (int r = 0; r < 4; ++r) {
            const int row = brow + wv * 32 + m * 16 + r4 + r;
            const float gi = acc[m][0][r] + b0;
            const float gf = acc[m][1][r] + b1;
            const float gg = acc[m][2][r] + b2;
            const float go = acc[m][3][r] + b3;
            const size_t ci = (size_t)row * 256 + unit;
            const float c2 = sigm(gf) * c[ci] + sigm(gi) * tanhf(gg);
            const float h2 = sigm(go) * tanhf(c2);
            c[ci] = c2;
            ps[m][r] = h2 * awe;
            const __hip_bfloat16 hb = __float2bfloat16(h2);
            hb1[(size_t)row * s1 + unit] = hb;
            hb2[(size_t)row * s2 + unit] = hb;
        }
    }
    if (score) {
        #pragma unroll
        for (int m = 0; m < 2; ++m) {
            #pragma unroll
            for (int r = 0; r < 4; ++r) {
                float v = ps[m][r];
                v += __shfl_xor(v, 1);
                v += __shfl_xor(v, 2);
                v += __shfl_xor(v, 4);
                v += __shfl_xor(v, 8);
                if (l16 == 0) {
                    const int row = brow + wv * 32 + m * 16 + r4 + r;
                    atomicAdd(&score[(size_t)row * S], v);
                }
            }
        }
    }
}

// ---------------------------------------------------------------------------
// Decoder fused GEMM + LSTM cell: K=256 (h @ Whh^T), per-ROW gate bias gctx.
// ---------------------------------------------------------------------------
__global__ __launch_bounds__(256, 2) void gemm_lstm_dec(
    const __hip_bfloat16* __restrict__ A,      // hdec[t&1], B x 256 bf16
    const __hip_bfloat16* __restrict__ W,      // Wdh, 1024 x 256 (permuted)
    const float* __restrict__ gctx,            // B x 1024 (permuted cols)
    float* __restrict__ c,
    __hip_bfloat16* __restrict__ hb1,          // hdec[(t+1)&1], stride 256
    __hip_bfloat16* __restrict__ hb2, int s2,  // dec_out + t*256, stride 3328
    int K)
{
    P_DECL();
    int bx, by;
    swz_decode(blockIdx.x, gridDim.x, 16, bx, by);
    const int brow = by * 128, bcol = bx * 64;
    const __hip_bfloat16* Ag = A + (size_t)brow * K;
    const __hip_bfloat16* Wg = W + (size_t)bcol * K;
    f32x4 acc[2][4] = {};

    PIPELINE(K);

    const int r4 = (lane >> 4) * 4;
    const int unit = bx * 16 + l16;
    #pragma unroll
    for (int m = 0; m < 2; ++m) {
        #pragma unroll
        for (int r = 0; r < 4; ++r) {
            const int row = brow + wv * 32 + m * 16 + r4 + r;
            const float* g = gctx + (size_t)row * NG + bcol;
            const float gi = acc[m][0][r] + g[l16];
            const float gf = acc[m][1][r] + g[16 + l16];
            const float gg = acc[m][2][r] + g[32 + l16];
            const float go = acc[m][3][r] + g[48 + l16];
            const size_t ci = (size_t)row * 256 + unit;
            const float c2 = sigm(gf) * c[ci] + sigm(gi) * tanhf(gg);
            const float h2 = sigm(go) * tanhf(c2);
            c[ci] = c2;
            const __hip_bfloat16 hb = __float2bfloat16(h2);
            hb1[(size_t)row * 256 + unit] = hb;
            hb2[(size_t)row * s2 + unit] = hb;
        }
    }
}

// ---------------------------------------------------------------------------
// 256x256 counted-vmcnt GEMM (FC2): BK=32, 8 waves (2Mx4N), 4-buffer LDS
// rotation (128 KB), depth-3 prefetch, slot-XOR swizzle, setprio.
// Super-tiled XCD grid map (R12). R17: removed the two vestigial internal
// barriers per K-tile (4-buffer invariant makes them unnecessary: staging
// targets buf cur-1, freed at the barrier ending tile t-1) — only one
// vmcnt(8)+barrier per tile, same invariant as the proven small PIPELINE.
// ---------------------------------------------------------------------------
__global__ __launch_bounds__(512, 2) void gemm256(
    const __hip_bfloat16* __restrict__ A,
    const __hip_bfloat16* __restrict__ W,
    const float* __restrict__ bias,
    float* __restrict__ Cf,
    int N, int K, int ldc, int nx)
{
    __shared__ __hip_bfloat16 As[4][256 * 32];
    __shared__ __hip_bfloat16 Bs[4][256 * 32];
    const int tid  = threadIdx.x;
    const int lane = tid & 63;
    const int wv = tid >> 6, wr = wv >> 2, wc = wv & 3;
    const int l16 = lane & 15;
    int bx, by;
    {   // super-tiled XCD map: xcd -> 10 sequential 4x4 super-tiles
        const int xcd = blockIdx.x & 7;
        const int lid = blockIdx.x >> 3;
        const int st  = lid >> 4;
        const int w   = lid & 15;
        const int gst = xcd * 10 + st;
        const int sbx = gst >> 2;
        const int sby = gst & 3;
        bx = sbx * 4 + (w & 3);
        by = sby * 4 + (w >> 2);
    }
    const int brow = by * 256, bcol = bx * 256;
    const __hip_bfloat16* Ag = A + (size_t)brow * K;
    const __hip_bfloat16* Wg = W + (size_t)bcol * K;
    const int sr = tid >> 2;
    const int sc = (((tid & 3) ^ ((tid >> 3) & 3)) << 3);
    const int sd = tid * 8;
    const int sl = (((lane >> 4) ^ ((l16 >> 1) & 3)) << 3);
    f32x4 acc[8][4] = {};
    const int nk = K >> 5;

    #define STG_A(buf, k0) do { \
        g2l16(&As[buf][sd],        Ag + (size_t)sr * K + (k0) + sc);         \
        g2l16(&As[buf][4096 + sd], Ag + (size_t)(sr + 128) * K + (k0) + sc); } while (0)
    #define STG_B(buf, k0) do { \
        g2l16(&Bs[buf][sd],        Wg + (size_t)sr * K + (k0) + sc);         \
        g2l16(&Bs[buf][4096 + sd], Wg + (size_t)(sr + 128) * K + (k0) + sc); } while (0)

    // One K-tile: frag reads from stable buf cur; staging into buf cur-1
    // (safe, 4-buffer); NO internal barriers — waves flow freely.
    #define TILE(cur, stg, k2, DO_STG) do {                                    \
        const __hip_bfloat16* Ab = As[cur];                                    \
        const __hip_bfloat16* Bb = Bs[cur];                                    \
        bf16x8 bfr[4], af[4];                                                  \
        _Pragma("unroll") for (int n = 0; n < 4; ++n)                          \
            bfr[n] = *(const bf16x8*)(Bb + (wc * 64 + n * 16 + l16) * 32 + sl);\
        _Pragma("unroll") for (int m = 0; m < 4; ++m)                          \
            af[m] = *(const bf16x8*)(Ab + (wr * 128 + m * 16 + l16) * 32 + sl);\
        if (DO_STG) STG_A(stg, k2);                                            \
        __builtin_amdgcn_s_setprio(1);                                         \
        _Pragma("unroll") for (int m = 0; m < 4; ++m)                          \
            _Pragma("unroll") for (int n = 0; n < 4; ++n)                      \
                acc[m][n] = __builtin_amdgcn_mfma_f32_16x16x32_bf16(           \
                    af[m], bfr[n], acc[m][n], 0, 0, 0);                        \
        __builtin_amdgcn_s_setprio(0);                                         \
        _Pragma("unroll") for (int m = 0; m < 4; ++m)                          \
            af[m] = *(const bf16x8*)(Ab + (wr * 128 + (m + 4) * 16 + l16) * 32 + sl); \
        if (DO_STG) STG_B(stg, k2);                                            \
        __builtin_amdgcn_s_setprio(1);                                         \
        _Pragma("unroll") for (int m = 0; m < 4; ++m)                          \
            _Pragma("unroll") for (int n = 0; n < 4; ++n)                      \
                acc[m + 4][n] = __builtin_amdgcn_mfma_f32_16x16x32_bf16(       \
                    af[m], bfr[n], acc[m + 4][n], 0, 0, 0);                    \
        __builtin_amdgcn_s_setprio(0);                                         \
    } while (0)

    STG_A(0, 0);  STG_B(0, 0);
    STG_A(1, 32); STG_B(1, 32);
    STG_A(2, 64); STG_B(2, 64);
    asm volatile("s_waitcnt vmcnt(8)" ::: "memory");
    BAR();
    int cur = 0;
    for (int t = 0; t < nk - 3; ++t) {
        const int stg = (cur + 3) & 3;
        TILE(cur, stg, (t + 3) << 5, true);
        asm volatile("s_waitcnt vmcnt(8)" ::: "memory");
        BAR();
        cur = (cur + 1) & 3;
    }
    TILE(cur, 0, 0, false);
    asm volatile("s_waitcnt vmcnt(4)" ::: "memory");
    BAR();
    cur = (cur + 1) & 3;
    TILE(cur, 0, 0, false);
    asm volatile("s_waitcnt vmcnt(0)" ::: "memory");
    BAR();
    cur = (cur + 1) & 3;
    TILE(cur, 0, 0, false);

    const int r4 = (lane >> 4) * 4;
    #pragma unroll
    for (int m = 0; m < 8; ++m) {
        #pragma unroll
        for (int n = 0; n < 4; ++n) {
            const int col = bcol + wc * 64 + n * 16 + l16;
            if (col >= N) continue;
            const float bv = bias[col];
            #pragma unroll
            for (int r = 0; r < 4; ++r) {
                const int row = brow + wr * 128 + m * 16 + r4 + r;
                Cf[(size_t)row * ldc + col] = acc[m][n][r] + bv;
            }
        }
    }
}

// ---------------------------------------------------------------------------
// Merged prep kernel (region-partitioned).
// ---------------------------------------------------------------------------
__device__ __forceinline__ int unperm(int np) {
    const int u = ((np >> 6) << 4) + (np & 15);
    const int g = (np >> 4) & 3;
    return g * 256 + u;
}

#define N_W2   ((long long)MELP * 1024 / 8)
#define N_W1   ((long long)NG * 3328 / 8)
#define N_WE   ((long long)NG * 384 / 8)
#define N_WD   ((long long)NG * 512 / 8)
#define N_EMB  ((long long)B * S * 32)
#define N_INIT ((long long)B * 256)
#define N_F2B  ((long long)MELP)
#define N_BP   ((long long)NG)
#define N_ES   ((long long)B * S)
#define N_PREP (N_W2 + N_W1 + N_WE + N_WD + N_EMB + N_INIT + N_F2B + N_BP + N_ES)

__global__ void prep_all(
    const int* __restrict__ text, const float* __restrict__ surp,
    const float* __restrict__ emb, const float* __restrict__ sw,
    const float* __restrict__ sb,
    const float* __restrict__ ew_ih, const float* __restrict__ ew_hh,
    const float* __restrict__ eb_ih, const float* __restrict__ eb_hh,
    const float* __restrict__ dw_ih, const float* __restrict__ dw_hh,
    const float* __restrict__ db_ih, const float* __restrict__ db_hh,
    const float* __restrict__ f1w, const float* __restrict__ f2w,
    const float* __restrict__ f2b, const float* __restrict__ init_in,
    const float* __restrict__ ab,
    __hip_bfloat16* __restrict__ Wenc,
    __hip_bfloat16* __restrict__ Wdc, __hip_bfloat16* __restrict__ Wdh,
    __hip_bfloat16* __restrict__ W1, __hip_bfloat16* __restrict__ W2,
    float* __restrict__ f2bp, float* __restrict__ be, float* __restrict__ bd,
    __hip_bfloat16* __restrict__ xall, float* __restrict__ c_buf,
    float* __restrict__ enc_score)
{
    long long id = (long long)blockIdx.x * 256 + threadIdx.x;
    if (id < N_W2) {
        const long long i8 = id * 8;
        bf16x8 v;
        if (i8 < (long long)MEL * 1024) {
            v = cvt8(*(const f32x4*)(f2w + i8), *(const f32x4*)(f2w + i8 + 4));
        } else {
            union { bf16x8 w; __hip_bfloat16 e[8]; } u;
            #pragma unroll
            for (int j = 0; j < 8; ++j) u.e[j] = __float2bfloat16(0.0f);
            v = u.w;
        }
        *(bf16x8*)(W2 + i8) = v;
        return;
    }
    id -= N_W2;
    if (id < N_W1) {
        const long long i8 = id * 8;
        *(bf16x8*)(W1 + i8) = cvt8(*(const f32x4*)(f1w + i8), *(const f32x4*)(f1w + i8 + 4));
        return;
    }
    id -= N_W1;
    if (id < N_WE) {
        const int idx = (int)(id * 8);
        const int np = idx / 384, k = idx % 384;
        const int n = unperm(np);
        const float* src = (k < 128) ? (ew_ih + n * 128 + k) : (ew_hh + n * 256 + (k - 128));
        *(bf16x8*)(Wenc + idx) = cvt8(*(const f32x4*)src, *(const f32x4*)(src + 4));
        return;
    }
    id -= N_WE;
    if (id < N_WD) {    // split pack: Wdc (ctx part) | Wdh (hh part)
        const int idx = (int)(id * 8);
        const int np = idx / 512, k = idx % 512;
        const int n = unperm(np);
        if (k < 256) {
            const float* src = dw_ih + n * 384 + 128 + k;
            *(bf16x8*)(Wdc + np * 256 + k) = cvt8(*(const f32x4*)src, *(const f32x4*)(src + 4));
        } else {
            const float* src = dw_hh + n * 256 + (k - 256);
            *(bf16x8*)(Wdh + np * 256 + (k - 256)) = cvt8(*(const f32x4*)src, *(const f32x4*)(src + 4));
        }
        return;
    }
    id -= N_WD;
    if (id < N_EMB) {
        const int idx = (int)id;
        const int jj = (idx & 31) * 4;
        const int rest = idx >> 5;
        const int b = rest % B;
        const int s = rest / B;
        const float sp = surp[b * S + s];
        const f32x4 e4 = *(const f32x4*)(emb + (size_t)text[b * S + s] * 128 + jj);
        const f32x4 w4 = *(const f32x4*)(sw + jj);
        const f32x4 b4 = *(const f32x4*)(sb + jj);
        __hip_bfloat16* dst = xall + ((size_t)s * B + b) * 384 + jj;
        #pragma unroll
        for (int i = 0; i < 4; ++i) dst[i] = __float2bfloat16(e4[i] + sp * w4[i] + b4[i]);
        return;
    }
    id -= N_EMB;
    if (id < N_INIT) {
        const int idx = (int)id;
        c_buf[idx] = 0.0f;
        const int b = idx >> 8, jj = idx & 255;
        xall[(size_t)b * 384 + 128 + jj] = __float2bfloat16(0.0f);
        return;
    }
    id -= N_INIT;
    if (id < N_F2B) {
        const int idx = (int)id;
        f2bp[idx] = (idx < MEL) ? f2b[idx] : 0.0f;
        return;
    }
    id -= N_F2B;
    if (id < N_BP) {
        const int np = (int)id;
        const int n = unperm(np);
        be[np] = eb_ih[n] + eb_hh[n];
        float s = db_ih[n] + db_hh[n];
        for (int k = 0; k < 128; ++k) s += dw_ih[n * 384 + k] * init_in[k];
        bd[np] = s;
        return;
    }
    id -= N_BP;
    if (id < N_ES) {
        enc_score[id] = ab[0];
        return;
    }
}

// ---------------------------------------------------------------------------
// One-shot attention: w = softmax(enc_score[b,:]) (h-independent — softmax is
// shift-invariant per row); context[b,:] = sum_s w[s] * enc_out[b,s,:].
// ---------------------------------------------------------------------------
__global__ void attn_once(const __hip_bfloat16* __restrict__ enc_out,
                          const float* __restrict__ enc_score,
                          __hip_bfloat16* __restrict__ ctx) {
    int b = (blockIdx.x * 256 + threadIdx.x) >> 6;
    int lane = threadIdx.x & 63;
    if (b >= B) return;
    float sc[S], mx = -1e30f;
    #pragma unroll
    for (int t = 0; t < S; ++t) { sc[t] = enc_score[b * S + t]; mx = fmaxf(mx, sc[t]); }
    float sum = 0.0f;
    #pragma unroll
    for (int t = 0; t < S; ++t) { sc[t] = expf(sc[t] - mx); sum += sc[t]; }
    const float inv = 1.0f / sum;
    float c0 = 0.f, c1 = 0.f, c2 = 0.f, c3 = 0.f;
    #pragma unroll
    for (int t = 0; t < S; ++t) {
        const ushort4 e4 = *(const ushort4*)(enc_out + ((size_t)b * S + t) * 256 + lane * 4);
        const float w = sc[t] * inv;
        c0 += w * b2f(e4.x); c1 += w * b2f(e4.y);
        c2 += w * b2f(e4.z); c3 += w * b2f(e4.w);
    }
    ushort4 o4 = { f2bu(c0), f2bu(c1), f2bu(c2), f2bu(c3) };
    *(ushort4*)(ctx + (size_t)b * 256 + lane * 4) = o4;
}

// ---------------------------------------------------------------------------
#define CDIV(a, b) (((a) + (b) - 1) / (b))

extern "C" void kernel_launch(void* const* d_in, const int* in_sizes, int n_in,
                              void* d_out, int out_size, void* d_ws, size_t ws_size,
                              hipStream_t stream) {
    const int*   text    = (const int*)  d_in[0];
    const float* surp    = (const float*)d_in[1];
    const float* emb     = (const float*)d_in[2];
    const float* sw      = (const float*)d_in[3];
    const float* sb      = (const float*)d_in[4];
    const float* ew_ih   = (const float*)d_in[5];
    const float* ew_hh   = (const float*)d_in[6];
    const float* eb_ih   = (const float*)d_in[7];
    const float* eb_hh   = (const float*)d_in[8];
    const float* aw      = (const float*)d_in[9];
    const float* ab      = (const float*)d_in[10];
    const float* dw_ih   = (const float*)d_in[11];
    const float* dw_hh   = (const float*)d_in[12];
    const float* db_ih   = (const float*)d_in[13];
    const float* db_hh   = (const float*)d_in[14];
    const float* f1w     = (const float*)d_in[15];
    const float* f1b     = (const float*)d_in[16];
    const float* f2w     = (const float*)d_in[17];
    const float* f2b     = (const float*)d_in[18];
    const float* init_in = (const float*)d_in[19];
    float* out = (float*)d_out;

    char* p = (char*)d_ws;
    auto alloc = [&](size_t bytes) {
        void* r = (void*)p;
        p += (bytes + 255) & ~(size_t)255;
        return r;
    };
    __hip_bfloat16* Wenc      = (__hip_bfloat16*)alloc((size_t)NG * 384 * 2);
    __hip_bfloat16* Wdc       = (__hip_bfloat16*)alloc((size_t)NG * 256 * 2);
    __hip_bfloat16* Wdh       = (__hip_bfloat16*)alloc((size_t)NG * 256 * 2);
    __hip_bfloat16* W1        = (__hip_bfloat16*)alloc((size_t)NG * 3328 * 2);
    __hip_bfloat16* W2        = (__hip_bfloat16*)alloc((size_t)MELP * 1024 * 2);
    float*          f2bp      = (float*)alloc((size_t)MELP * 4);
    float*          be        = (float*)alloc((size_t)NG * 4);
    float*          bd        = (float*)alloc((size_t)NG * 4);
    __hip_bfloat16* xall      = (__hip_bfloat16*)alloc((size_t)S * B * 384 * 2);
    __hip_bfloat16* enc_out   = (__hip_bfloat16*)alloc((size_t)B * S * 256 * 2);
    float*          enc_score = (float*)alloc((size_t)B * S * 4);
    float*          c_buf     = (float*)alloc((size_t)B * 256 * 4);
    __hip_bfloat16* ctx       = (__hip_bfloat16*)alloc((size_t)B * 256 * 2);
    float*          gctx      = (float*)alloc((size_t)B * NG * 4);
    __hip_bfloat16* hdec      = (__hip_bfloat16*)alloc((size_t)2 * B * 256 * 2);
    __hip_bfloat16* dec_out   = (__hip_bfloat16*)alloc((size_t)B * 3328 * 2);
    __hip_bfloat16* hfc       = (__hip_bfloat16*)alloc((size_t)B * 1024 * 2);
    (void)ws_size; (void)in_sizes; (void)n_in; (void)out_size;

    // --- merged prep ---
    prep_all<<<(int)CDIV(N_PREP, 256), 256, 0, stream>>>(
        text, surp, emb, sw, sb, ew_ih, ew_hh, eb_ih, eb_hh,
        dw_ih, dw_hh, db_ih, db_hh, f1w, f2w, f2b, init_in, ab,
        Wenc, Wdc, Wdh, W1, W2, f2bp, be, bd, xall, c_buf, enc_score);

    // --- encoder: 13 fused GEMM+cell steps (enc_score fused via atomics) ---
    for (int t = 0; t < S; ++t) {
        __hip_bfloat16* hb1; int s1;
        if (t < S - 1) { hb1 = xall + ((size_t)(t + 1) * B * 384) + 128; s1 = 384; }
        else           { hb1 = hdec; s1 = 256; }
        gemm_lstm3<<<512, 256, 0, stream>>>(
            xall + (size_t)t * B * 384, Wenc, be, c_buf,
            hb1, s1, enc_out + (size_t)t * 256, S * 256, 384,
            aw, enc_score + t);
    }

    // --- attention (once): context + its gate projection ---
    attn_once<<<CDIV(B * 64, 256), 256, 0, stream>>>(enc_out, enc_score, ctx);
    gemm3<<<(NG / 64) * (B / 128), 256, 0, stream>>>(
        ctx, Wdc, bd, gctx, (__hip_bfloat16*)nullptr, NG, 256, NG, 0, NG / 64);

    // --- decoder: 13 fused GEMM+cell steps, K=256, per-row bias gctx ---
    for (int t = 0; t < S; ++t) {
        gemm_lstm_dec<<<512, 256, 0, stream>>>(
            hdec + (size_t)(t & 1) * B * 256, Wdh, gctx, c_buf,
            hdec + (size_t)((t + 1) & 1) * B * 256,
            dec_out + (size_t)t * 256, 3328, 256);
    }

    // --- FC1: relu(dec_out @ f1w.T + f1b) -> bf16 hfc ---
    gemm3<<<(NG / 64) * (B / 128), 256, 0, stream>>>(
        dec_out, W1, f1b, (float*)nullptr, hfc, NG, 3328, NG, 1, NG / 64);

    // --- FC2: 256x256 counted-vmcnt kernel (super-tiled XCD map) -> out ---
    gemm256<<<(MELP / 256) * (B / 256), 512, 0, stream>>>(
        hfc, W2, f2bp, out, MEL, 1024, MEL, MELP / 256);
}